// Round 9
// baseline (454.350 us; speedup 1.0000x reference)
//
#include <hip/hip_runtime.h>

#define EDIM 1024
#define MROWS 16384
#define DHEAD 64
#define LSEQ 512
#define NT 16          // K tiles of 64
#define QSCL 0.18033688011112042f   // 0.125 * log2(e), folded into Wq/bq

typedef unsigned short u16;
typedef unsigned int u32;
typedef __bf16 bf16x8 __attribute__((ext_vector_type(8)));
typedef unsigned short u16x8 __attribute__((ext_vector_type(8)));
typedef float f32x4 __attribute__((ext_vector_type(4)));

__device__ __forceinline__ u16 f2bf(float x) {
    return __builtin_bit_cast(u16, (__bf16)x);          // RTNE via HW cvt
}
__device__ __forceinline__ float bf2f(u16 h) {
    return __builtin_bit_cast(float, (u32)h << 16);
}
__device__ __forceinline__ bf16x8 ld8(const u16* p) {
    return __builtin_bit_cast(bf16x8, *(const u16x8*)p);
}
// swizzled tile read: linear [R][64] u16, byte = row*128 + (2*koff ^ ((row&7)<<4))
__device__ __forceinline__ bf16x8 ld8s(const u16* base, int row, int koff) {
    return ld8((const u16*)((const char*)base + row * 128 + ((koff * 2) ^ ((row & 7) << 4))));
}
// V^T tile read: byte = c*128 + (2*koff ^ (((c>>2)&7)<<4))
__device__ __forceinline__ bf16x8 ld8v(const u16* base, int c, int koff) {
    return ld8((const u16*)((const char*)base + c * 128 + ((koff * 2) ^ (((c >> 2) & 7) << 4))));
}
__device__ __forceinline__ void glds16(const u16* g, u16* l) {
    __builtin_amdgcn_global_load_lds(
        (const __attribute__((address_space(1))) u32*)g,
        (__attribute__((address_space(3))) u32*)l, 16, 0, 0);
}
__device__ __forceinline__ u32 pk2(float a, float b) {
    return (u32)f2bf(a) | ((u32)f2bf(b) << 16);
}
__device__ __forceinline__ u32 dup2(float a) {
    u32 v = (u32)f2bf(a); return v | (v << 16);
}
#define MFMA(a, b, c) __builtin_amdgcn_mfma_f32_16x16x32_bf16((a), (b), (c), 0, 0, 0)
#define U4C(v, i) ((i) == 0 ? (v).x : (i) == 1 ? (v).y : (i) == 2 ? (v).z : (v).w)
#define VMCNT(n) asm volatile("s_waitcnt vmcnt(" #n ")" ::: "memory")
#define SBAR()   __builtin_amdgcn_s_barrier()

// ---------------------------------------------------------------------------
// Kernel 1: transpose + bf16 of the 4 weight matrices: WT[n][k] = bf16(W[k][n])
// z==0 (Wq) is pre-scaled by QSCL (exp2-domain scores).
// ---------------------------------------------------------------------------
__global__ __launch_bounds__(256) void prep_wt_kernel(
    const float* __restrict__ Wq, const float* __restrict__ Wk,
    const float* __restrict__ Wv, const float* __restrict__ Wo,
    u16* __restrict__ WTh)
{
    const int z = blockIdx.z;
    const float* W = (z == 0) ? Wq : (z == 1) ? Wk : (z == 2) ? Wv : Wo;
    const float scl = (z == 0) ? QSCL : 1.0f;
    u16* th = WTh + (size_t)z * EDIM * EDIM;
    const int k0 = blockIdx.x * 64, n0 = blockIdx.y * 64;
    __shared__ float tile[64][65];
    for (int i = threadIdx.x; i < 4096; i += 256) {
        int r = i >> 6, c = i & 63;
        tile[r][c] = W[(size_t)(k0 + r) * EDIM + n0 + c];
    }
    __syncthreads();
    for (int i = threadIdx.x; i < 4096; i += 256) {
        int r = i >> 6, c = i & 63;
        th[(size_t)(n0 + r) * EDIM + k0 + c] = f2bf(tile[c][r] * scl);
    }
}

// ---------------------------------------------------------------------------
// Kernel 2: fp32 -> bf16 convert of the three input matrices (z selects)
// ---------------------------------------------------------------------------
__global__ __launch_bounds__(256) void convert_kernel(
    const float* __restrict__ Aq, const float* __restrict__ Ak, const float* __restrict__ Av,
    u16* __restrict__ Dq, u16* __restrict__ Dk, u16* __restrict__ Dv)
{
    const int z = blockIdx.z;
    const float* src = (z == 0) ? Aq : (z == 1) ? Ak : Av;
    u16* dst = (z == 0) ? Dq : (z == 1) ? Dk : Dv;
    const size_t total8 = (size_t)MROWS * EDIM / 8;
    for (size_t i = (size_t)blockIdx.x * 256 + threadIdx.x; i < total8;
         i += (size_t)gridDim.x * 256) {
        const float4 a = *(const float4*)&src[i * 8];
        const float4 b = *(const float4*)&src[i * 8 + 4];
        ushort4 h0, h1;
        h0.x = f2bf(a.x); h0.y = f2bf(a.y); h0.z = f2bf(a.z); h0.w = f2bf(a.w);
        h1.x = f2bf(b.x); h1.y = f2bf(b.y); h1.z = f2bf(b.z); h1.w = f2bf(b.w);
        *(ushort4*)&dst[i * 8]     = h0;
        *(ushort4*)&dst[i * 8 + 4] = h1;
    }
}

// ---------------------------------------------------------------------------
// Kernel 3: 256x256x64 GEMM, 8 waves, counted-vmcnt 4-phase schedule (proven R7)
// bsc scales the bias (Q projection uses QSCL).
// ---------------------------------------------------------------------------
template<int EPI>
__global__ __launch_bounds__(512, 1) void gemm256(
    const u16* __restrict__ A, const u16* __restrict__ BT,
    const float* __restrict__ bias, float bsc,
    u16* __restrict__ Ch, float* __restrict__ Cf, const float* __restrict__ smask)
{
    extern __shared__ u16 lds[];           // 128 KiB: A[2][16384], B[2][16384]
    const int tid = threadIdx.x;
    const int lane = tid & 63, w = tid >> 6;
    const int wm = w >> 2, wn = w & 3;
    const int lr = lane & 15, lg = lane >> 4;
    int D = blockIdx.x;
    int T = (D & 7) * 32 + (D >> 3);
    const int m0 = (T >> 2) * 256, n0 = (T & 3) * 256;

    u16* As0 = lds;
    u16* As1 = lds + 16384;
    u16* Bs0 = lds + 32768;
    u16* Bs1 = lds + 49152;

    auto stageB = [&](int bf, int t) {
        u16* dst = bf ? Bs1 : Bs0;
        #pragma unroll
        for (int c = 0; c < 4; ++c) {
            int idx = tid + c * 512;
            int row = idx >> 3, ch = idx & 7, sch = ch ^ (row & 7);
            glds16(&BT[(size_t)(n0 + row) * EDIM + t * 64 + sch * 8], dst + idx * 8);
        }
    };
    auto stageA = [&](int bf, int t) {
        u16* dst = bf ? As1 : As0;
        #pragma unroll
        for (int c = 0; c < 4; ++c) {
            int idx = tid + c * 512;
            int row = idx >> 3, ch = idx & 7, sch = ch ^ (row & 7);
            glds16(&A[(size_t)(m0 + row) * EDIM + t * 64 + sch * 8], dst + idx * 8);
        }
    };

    f32x4 acc[8][4] = {};
    bf16x8 bf0[4], bf1[4];

    stageB(0, 0);
    stageA(0, 0);
    VMCNT(0);
    SBAR();
    #pragma unroll
    for (int n = 0; n < 4; ++n)
        bf0[n] = ld8s(Bs0, wn * 64 + n * 16 + lr, lg * 8);

    for (int t = 0; t < NT; ++t) {
        const int cur = t & 1;
        u16* Asc = cur ? As1 : As0;
        u16* Bsc = cur ? Bs1 : Bs0;
        u16* Bsn = cur ? Bs0 : Bs1;
        const bool more = (t + 1 < NT);
        // ---- q0 ----
        bf16x8 af[4];
        #pragma unroll
        for (int mm = 0; mm < 4; ++mm)
            af[mm] = ld8s(Asc, wm * 128 + mm * 16 + lr, lg * 8);
        if (more) { stageB(cur ^ 1, t + 1); stageA(cur ^ 1, t + 1); }
        SBAR();
        __builtin_amdgcn_s_setprio(1);
        #pragma unroll
        for (int n = 0; n < 4; ++n)
            #pragma unroll
            for (int mm = 0; mm < 4; ++mm)
                acc[mm][n] = MFMA(af[mm], bf0[n], acc[mm][n]);
        __builtin_amdgcn_s_setprio(0);
        SBAR();
        // ---- q1 ----
        bf16x8 ag[4];
        #pragma unroll
        for (int mm = 0; mm < 4; ++mm)
            ag[mm] = ld8s(Asc, wm * 128 + 64 + mm * 16 + lr, lg * 8);
        SBAR();
        __builtin_amdgcn_s_setprio(1);
        #pragma unroll
        for (int n = 0; n < 4; ++n)
            #pragma unroll
            for (int mm = 0; mm < 4; ++mm)
                acc[4 + mm][n] = MFMA(ag[mm], bf0[n], acc[4 + mm][n]);
        __builtin_amdgcn_s_setprio(0);
        SBAR();
        // ---- q2 ----
        #pragma unroll
        for (int mm = 0; mm < 4; ++mm)
            af[mm] = ld8s(Asc, wm * 128 + mm * 16 + lr, 32 + lg * 8);
        #pragma unroll
        for (int n = 0; n < 4; ++n)
            bf1[n] = ld8s(Bsc, wn * 64 + n * 16 + lr, 32 + lg * 8);
        SBAR();
        __builtin_amdgcn_s_setprio(1);
        #pragma unroll
        for (int n = 0; n < 4; ++n)
            #pragma unroll
            for (int mm = 0; mm < 4; ++mm)
                acc[mm][n] = MFMA(af[mm], bf1[n], acc[mm][n]);
        __builtin_amdgcn_s_setprio(0);
        VMCNT(4);
        SBAR();
        // ---- q3 ----
        #pragma unroll
        for (int mm = 0; mm < 4; ++mm)
            ag[mm] = ld8s(Asc, wm * 128 + 64 + mm * 16 + lr, 32 + lg * 8);
        if (more) {
            #pragma unroll
            for (int n = 0; n < 4; ++n)
                bf0[n] = ld8s(Bsn, wn * 64 + n * 16 + lr, lg * 8);
        }
        SBAR();
        __builtin_amdgcn_s_setprio(1);
        #pragma unroll
        for (int n = 0; n < 4; ++n)
            #pragma unroll
            for (int mm = 0; mm < 4; ++mm)
                acc[4 + mm][n] = MFMA(ag[mm], bf1[n], acc[4 + mm][n]);
        __builtin_amdgcn_s_setprio(0);
        VMCNT(0);
        SBAR();
    }
    #pragma unroll
    for (int m = 0; m < 8; ++m)
        #pragma unroll
        for (int n = 0; n < 4; ++n) {
            int col = n0 + wn * 64 + n * 16 + lr;
            float bc = bias[col];
            #pragma unroll
            for (int r = 0; r < 4; ++r) {
                int row = m0 + wm * 128 + m * 16 + lg * 4 + r;
                float x = acc[m][n][r];
                if (EPI == 1) {
                    float g = 1.0f / (1.0f + __expf(-smask[row & (LSEQ - 1)]));
                    Cf[(size_t)row * EDIM + col] = (x + 2.0f * bc) * g;
                } else {
                    Ch[(size_t)row * EDIM + col] = f2bf(x + bsc * bc);
                }
            }
        }
}

// ---------------------------------------------------------------------------
// Kernel 4: ALL attention in one pass over 512 keys.  128 q-rows per block
// (4 waves x 32), exp2-domain scores (scale folded into Wq/bq).
// Level-l P duplication with weights folded into final normalizers.
// ---------------------------------------------------------------------------
__global__ __launch_bounds__(256, 2) void attn_kernel(
    const u16* __restrict__ Q, const u16* __restrict__ K,
    const u16* __restrict__ V, u16* __restrict__ ctx)
{
    extern __shared__ u16 alds[];          // Ks[2]:16KB, Vt:8KB, Ps:4*13824B
    const int tid = threadIdx.x, lane = tid & 63, w = tid >> 6;
    const int lr = lane & 15, lg = lane >> 4;
    int D = blockIdx.x;                    // 2048 = 8 XCD * 256
    int T = (D & 7) * 256 + (D >> 3);
    const int qq = T & 3, hd = (T >> 2) & 15, b = T >> 6;
    const int wrow = b * LSEQ + qq * 128 + w * 32;
    const int ecol = hd * DHEAD;
    const int kvbase = b * LSEQ;
    const int wt0 = qq * 2;                // window tiles wt0, wt0+1

    u16* Ks0 = alds;
    u16* Ks1 = alds + 4096;
    u16* Vt  = alds + 8192;
    char* psw = (char*)(alds + 12288) + w * 13824;   // 3 lvl * 32 q * 144B

    bf16x8 qf[2][2];
    #pragma unroll
    for (int m = 0; m < 2; ++m)
        #pragma unroll
        for (int ks = 0; ks < 2; ++ks)
            qf[m][ks] = ld8(&Q[(size_t)(wrow + m * 16 + lr) * EDIM + ecol + ks * 32 + lg * 8]);

    f32x4 o0[2][4] = {}, o1[2][4] = {}, o2[2][4] = {}, ow[2][4] = {};
    float l0[2] = {}, l1[2] = {}, l2[2] = {}, lw[2] = {};
    ushort4 vr[2][2];

    auto issueK = [&](int t, int bf) {
        u16* dst = bf ? Ks1 : Ks0;
        #pragma unroll
        for (int c = 0; c < 2; ++c) {
            int idx = tid + c * 256;
            int row = idx >> 3, ch = idx & 7;
            int sch = ch ^ (row & 7);
            glds16(&K[(size_t)(kvbase + t * 64 + row) * EDIM + ecol + sch * 8],
                   dst + idx * 8);
        }
    };
    auto loadV = [&](int t) {
        #pragma unroll
        for (int j = 0; j < 2; ++j) {
            int i4 = tid + j * 256;
            int pr = i4 >> 4, c4 = (i4 & 15) << 2;
            vr[j][0] = *(const ushort4*)&V[(size_t)(kvbase + t * 64 + 2 * pr) * EDIM + ecol + c4];
            vr[j][1] = *(const ushort4*)&V[(size_t)(kvbase + t * 64 + 2 * pr + 1) * EDIM + ecol + c4];
        }
    };
    auto writeV = [&]() {
        #pragma unroll
        for (int j = 0; j < 2; ++j) {
            int i4 = tid + j * 256;
            int pr = i4 >> 4, c4 = (i4 & 15) << 2;
            #pragma unroll
            for (int i = 0; i < 4; ++i) {
                int c = c4 + i;
                int byo = c * 128 + ((4 * pr) ^ (((c >> 2) & 7) << 4));
                *(u32*)((char*)Vt + byo) =
                    (u32)U4C(vr[j][0], i) | ((u32)U4C(vr[j][1], i) << 16);
            }
        }
    };

    int buf = 0;
    issueK(0, 0);
    loadV(0);
    for (int t = 0; t < 8; ++t) {
        __syncthreads();                    // drains glds K(t) + V-reg loads
        writeV();
        __syncthreads();                    // K(t), Vt(t) visible
        if (t < 7) { issueK(t + 1, buf ^ 1); loadV(t + 1); }
        const bool win = (t == wt0) | (t == wt0 + 1);
        u16* Ksc = buf ? Ks1 : Ks0;

        float l0t[2] = {};
        #pragma unroll
        for (int nb = 0; nb < 4; ++nb) {
            bf16x8 kf0 = ld8s(Ksc, nb * 16 + lr, lg * 8);
            bf16x8 kf1 = ld8s(Ksc, nb * 16 + lr, 32 + lg * 8);
            #pragma unroll
            for (int m = 0; m < 2; ++m) {
                f32x4 s = {};
                s = MFMA(kf0, qf[m][0], s);   // S^T: rows=keys, cols=q (q = lr)
                s = MFMA(kf1, qf[m][1], s);
                float p00 = exp2f(s[0]), p01 = exp2f(s[1]);
                float p02 = exp2f(s[2]), p03 = exp2f(s[3]);
                float s1a = 0.5f * (s[0] + s[1]), s1b = 0.5f * (s[2] + s[3]);
                float p1a = exp2f(s1a), p1b = exp2f(s1b);
                float p2v = exp2f(0.5f * (s1a + s1b));
                l0t[m] += (p00 + p01) + (p02 + p03);
                l1[m] += p1a + p1b;
                l2[m] += p2v;
                char* pb = psw + (m * 16 + lr) * 144 + nb * 32 + lg * 8;
                *(u32*)pb           = pk2(p00, p01);
                *(u32*)(pb + 4)     = pk2(p02, p03);
                *(u32*)(pb + 4608)  = dup2(p1a);
                *(u32*)(pb + 4612)  = dup2(p1b);
                u32 w2 = dup2(p2v);
                *(u32*)(pb + 9216)  = w2;
                *(u32*)(pb + 9220)  = w2;
            }
        }
        l0[0] += l0t[0]; l0[1] += l0t[1];
        if (win) { lw[0] += l0t[0]; lw[1] += l0t[1]; }

        bf16x8 vb[4][2];
        #pragma unroll
        for (int nd = 0; nd < 4; ++nd) {
            vb[nd][0] = ld8v(Vt, nd * 16 + lr, lg * 8);
            vb[nd][1] = ld8v(Vt, nd * 16 + lr, 32 + lg * 8);
        }
        #pragma unroll
        for (int m = 0; m < 2; ++m) {
            char* pb = psw + (m * 16 + lr) * 144;
            bf16x8 pa00 = ld8((const u16*)(pb + lg * 16));
            bf16x8 pa01 = ld8((const u16*)(pb + 64 + lg * 16));
            bf16x8 pa10 = ld8((const u16*)(pb + 4608 + lg * 16));
            bf16x8 pa11 = ld8((const u16*)(pb + 4672 + lg * 16));
            bf16x8 pa20 = ld8((const u16*)(pb + 9216 + lg * 16));
            bf16x8 pa21 = ld8((const u16*)(pb + 9280 + lg * 16));
            #pragma unroll
            for (int nd = 0; nd < 4; ++nd) {
                o0[m][nd] = MFMA(pa00, vb[nd][0], o0[m][nd]);
                o0[m][nd] = MFMA(pa01, vb[nd][1], o0[m][nd]);
                o1[m][nd] = MFMA(pa10, vb[nd][0], o1[m][nd]);
                o1[m][nd] = MFMA(pa11, vb[nd][1], o1[m][nd]);
                o2[m][nd] = MFMA(pa20, vb[nd][0], o2[m][nd]);
                o2[m][nd] = MFMA(pa21, vb[nd][1], o2[m][nd]);
                if (win) {
                    ow[m][nd] = MFMA(pa00, vb[nd][0], ow[m][nd]);
                    ow[m][nd] = MFMA(pa01, vb[nd][1], ow[m][nd]);
                }
            }
        }
        buf ^= 1;
    }
    // epilogue: finish l-sums across lg groups; level weights folded here
    #pragma unroll
    for (int m = 0; m < 2; ++m) {
        l0[m] += __shfl_xor(l0[m], 16, 64); l0[m] += __shfl_xor(l0[m], 32, 64);
        l1[m] += __shfl_xor(l1[m], 16, 64); l1[m] += __shfl_xor(l1[m], 32, 64);
        l2[m] += __shfl_xor(l2[m], 16, 64); l2[m] += __shfl_xor(l2[m], 32, 64);
        lw[m] += __shfl_xor(lw[m], 16, 64); lw[m] += __shfl_xor(lw[m], 32, 64);
        float c0 = (1.0f / 3.0f) / l0[m];
        float c1 = (1.0f / 6.0f) / l1[m];        // (1/3)/(2 l1): pair-dup factor
        float c2 = (1.0f / 12.0f) / l2[m];       // (1/3)/(4 l2): quad-dup factor
        float cw = 1.0f / lw[m];
        #pragma unroll
        for (int r = 0; r < 4; ++r) {
            int src = lg * 4 + r;                // q-row of D-reg r lives on lane src
            float d0 = __shfl(c0, src, 64);
            float d1 = __shfl(c1, src, 64);
            float d2 = __shfl(c2, src, 64);
            float dw = __shfl(cw, src, 64);
            #pragma unroll
            for (int nd = 0; nd < 4; ++nd) {
                float v = o0[m][nd][r] * d0 + o1[m][nd][r] * d1
                        + o2[m][nd][r] * d2 + ow[m][nd][r] * dw;
                ctx[(size_t)(wrow + m * 16 + lg * 4 + r) * EDIM + ecol + nd * 16 + lr] = f2bf(v);
            }
        }
    }
}

// ---------------------------------------------------------------------------
extern "C" void kernel_launch(void* const* d_in, const int* in_sizes, int n_in,
                              void* d_out, int out_size, void* d_ws, size_t ws_size,
                              hipStream_t stream)
{
    const float* query = (const float*)d_in[0];
    const float* key   = (const float*)d_in[1];
    const float* value = (const float*)d_in[2];
    const float* Wq = (const float*)d_in[3];
    const float* bq = (const float*)d_in[4];
    const float* Wk = (const float*)d_in[5];
    const float* bk = (const float*)d_in[6];
    const float* Wv = (const float*)d_in[7];
    const float* bv = (const float*)d_in[8];
    const float* Wo = (const float*)d_in[9];
    const float* bo = (const float*)d_in[10];
    const float* smask = (const float*)d_in[11];

    const size_t szWT = (size_t)4 * EDIM * EDIM * 2;   // 8 MiB
    const size_t szP  = (size_t)MROWS * EDIM * 2;      // 32 MiB (bf16 plane)
    const size_t need = szWT + 7 * szP;                // 232 MiB
    if (ws_size < need) {
        hipMemsetAsync(d_out, 0x7F, (size_t)out_size * 4, stream);  // sentinel
        return;
    }
    size_t off = 0;
    auto take = [&](size_t n) -> void* {
        void* p = (char*)d_ws + off;
        off += (n + 255) & ~(size_t)255;
        return p;
    };
    u16* WTh = (u16*)take(szWT);
    u16* Aq  = (u16*)take(szP);     // bf16 inputs
    u16* Ak  = (u16*)take(szP);
    u16* Av  = (u16*)take(szP);
    u16* Qh  = (u16*)take(szP);     // projected
    u16* Kh  = (u16*)take(szP);
    u16* Vh  = (u16*)take(szP);
    u16* ctx = (u16*)take(szP);

    (void)hipFuncSetAttribute(reinterpret_cast<const void*>(gemm256<0>),
                              hipFuncAttributeMaxDynamicSharedMemorySize, 131072);
    (void)hipFuncSetAttribute(reinterpret_cast<const void*>(gemm256<1>),
                              hipFuncAttributeMaxDynamicSharedMemorySize, 131072);
    (void)hipFuncSetAttribute(reinterpret_cast<const void*>(attn_kernel),
                              hipFuncAttributeMaxDynamicSharedMemorySize, 81920);

    prep_wt_kernel<<<dim3(16, 16, 4), 256, 0, stream>>>(Wq, Wk, Wv, Wo, WTh);
    convert_kernel<<<dim3(4096, 1, 3), 256, 0, stream>>>(query, key, value, Aq, Ak, Av);

    gemm256<0><<<256, 512, 131072, stream>>>(
        Aq, WTh + 0 * (size_t)EDIM * EDIM, bq, QSCL, Qh, nullptr, nullptr);
    gemm256<0><<<256, 512, 131072, stream>>>(
        Ak, WTh + 1 * (size_t)EDIM * EDIM, bk, 1.0f, Kh, nullptr, nullptr);
    gemm256<0><<<256, 512, 131072, stream>>>(
        Av, WTh + 2 * (size_t)EDIM * EDIM, bv, 1.0f, Vh, nullptr, nullptr);

    attn_kernel<<<2048, 256, 79872, stream>>>(Qh, Kh, Vh, ctx);

    gemm256<1><<<256, 512, 131072, stream>>>(
        ctx, WTh + 3 * (size_t)EDIM * EDIM, bo, 1.0f, nullptr, (float*)d_out, smask);
}